// Round 5
// baseline (351.695 us; speedup 1.0000x reference)
//
#include <hip/hip_runtime.h>

#define F_IN 128
#define DIM_H 256
#define N_CLASSES 40
#define BN_EPS 1e-5f
#define M_PAD 50176

typedef short bf16x8 __attribute__((ext_vector_type(8)));
typedef float f32x4 __attribute__((ext_vector_type(4)));

__device__ __forceinline__ unsigned short f2bf(float f) {
    union { float f; unsigned u; } v; v.f = f;
    unsigned r = v.u + 0x7fff + ((v.u >> 16) & 1);  // RNE
    return (unsigned short)(r >> 16);
}
__device__ __forceinline__ float bf2f(unsigned short u) {
    union { unsigned u; float f; } v; v.u = ((unsigned)u) << 16;
    return v.f;
}
__device__ __forceinline__ float4 bf2f4(ushort4 u) {
    return make_float4(bf2f(u.x), bf2f(u.y), bf2f(u.z), bf2f(u.w));
}

// Grid-wide barrier (all blocks co-resident by capacity: 391 blocks,
// 2 blocks/CU x 256 CU = 512). Leader-thread release/acquire on a global
// flag; __threadfence = agent-scope (L2 writeback/invalidate on gfx950),
// the same pattern ROCm's grid.sync uses.
__device__ __forceinline__ void grid_barrier(int* cnt, int* flag, int nB) {
    __syncthreads();
    if (threadIdx.x == 0) {
        __threadfence();
        if (atomicAdd(cnt, 1) == nB - 1) {
            __hip_atomic_store(flag, 1, __ATOMIC_RELEASE, __HIP_MEMORY_SCOPE_AGENT);
        } else {
            while (__hip_atomic_load(flag, __ATOMIC_ACQUIRE, __HIP_MEMORY_SCOPE_AGENT) == 0) {
                __builtin_amdgcn_s_sleep(8);
            }
        }
        __threadfence();
    }
    __syncthreads();
}

// ---------------- Phase A: histogram of dst ----------------
__global__ void hist_kernel(const int* __restrict__ dst, int* __restrict__ hist, int nE) {
    int e = blockIdx.x * blockDim.x + threadIdx.x;
    if (e >= nE) return;
    atomicAdd(&hist[dst[e]], 1);
}

// ---------------- Phase B: single-kernel scan (fused blocks+final) ----------------
__global__ void scan_kernel(const int* __restrict__ hist,
                            int* __restrict__ start, int* __restrict__ cursor,
                            int M, int nE) {
    __shared__ int lds[256];
    __shared__ int s_prefix;
    int t = threadIdx.x;
    int base = blockIdx.x * 256;
    int s = 0;
    for (int i = t; i < base; i += 256) s += hist[i];
    lds[t] = s;
    __syncthreads();
    for (int o = 128; o > 0; o >>= 1) {
        if (t < o) lds[t] += lds[t + o];
        __syncthreads();
    }
    if (t == 0) s_prefix = lds[0];
    __syncthreads();
    int prefix = s_prefix;
    __syncthreads();           // lds reuse below
    int i = base + t;
    int orig = (i < M) ? hist[i] : 0;
    lds[t] = orig;
    __syncthreads();
    for (int o = 1; o < 256; o <<= 1) {
        int v = (t >= o) ? lds[t - o] : 0;
        __syncthreads();
        lds[t] += v;
        __syncthreads();
    }
    if (i < M) {
        int v = prefix + lds[t] - orig;
        start[i] = v;
        cursor[i] = v;
    }
    if (blockIdx.x == 0 && t == 0) start[M] = nE;
}

// ---------------- Phase C: bucket-fill src indices ----------------
__global__ void fill_kernel(const int* __restrict__ src, const int* __restrict__ dst,
                            int* __restrict__ cursor,
                            int* __restrict__ order, int nE) {
    int e = blockIdx.x * blockDim.x + threadIdx.x;
    if (e >= nE) return;
    int pos = atomicAdd(&cursor[dst[e]], 1);
    order[pos] = src[e];
}

// ---------------- prep: xb = bf16(x), weight transposes, hist+bar zeroing ----------------
__global__ void prep_kernel(const float* __restrict__ x, unsigned short* __restrict__ xb,
                            const float* __restrict__ W1, const float* __restrict__ W2,
                            const float* __restrict__ Wl,
                            unsigned short* __restrict__ W1t,
                            unsigned short* __restrict__ W2t,
                            unsigned short* __restrict__ Wlt,
                            int* __restrict__ histz, int XQ, int ZQ) {
    int idx = blockIdx.x * 256 + threadIdx.x;
    if (idx < XQ) {
        float4 v = ((const float4*)x)[idx];
        ushort4 o;
        o.x = f2bf(v.x); o.y = f2bf(v.y); o.z = f2bf(v.z); o.w = f2bf(v.w);
        ((ushort4*)xb)[idx] = o;
        return;
    }
    int j = idx - XQ;
    if (j < 32768) {                    // W1t: [n=256][k=128]
        int n = j >> 7, k = j & 127;
        W1t[j] = f2bf(W1[k * DIM_H + n]);
    } else if (j < 32768 + 65536) {     // W2t: [n=256][k=256]
        int i = j - 32768;
        int n = i >> 8, k = i & 255;
        W2t[i] = f2bf(W2[k * DIM_H + n]);
    } else if (j < 32768 + 65536 + 16384) {  // Wlt: [n=64][k=256]
        int i = j - 98304;
        int n = i >> 8, k = i & 255;
        Wlt[i] = f2bf((n < N_CLASSES) ? Wl[k * N_CLASSES + n] : 0.f);
    } else {
        int z = j - 114688;
        if (z >= 0 && z < ZQ) ((int4*)histz)[z] = make_int4(0, 0, 0, 0);
    }
}

// ---------------- standalone gather: A1 = bf16(x + agg) ----------------
// Half-wave per row, 8-deep independent row loads, next-batch index prefetch.
// Max occupancy (tiny VGPR/LDS) — the proven round-2 configuration.
__global__ __launch_bounds__(256) void gather_kernel(
    const unsigned short* __restrict__ xb,
    const int* __restrict__ order, const int* __restrict__ start,
    unsigned short* __restrict__ A1, int M) {
    int node = blockIdx.x * 8 + (threadIdx.x >> 5);
    if (node >= M) return;
    int lane32 = threadIdx.x & 31;
    const ushort4* xv = (const ushort4*)xb;
    float4 a0 = bf2f4(xv[(size_t)node * 32 + lane32]);  // self term
    float4 a1 = make_float4(0.f, 0.f, 0.f, 0.f);
    float4 a2 = a1, a3 = a1;
    int e0 = start[node], e1 = start[node + 1];
    int e = e0;
    int c0, c1, c2, c3, c4, c5, c6, c7;
    bool have = (e + 8 <= e1);
    if (have) {
        c0 = order[e];     c1 = order[e + 1]; c2 = order[e + 2]; c3 = order[e + 3];
        c4 = order[e + 4]; c5 = order[e + 5]; c6 = order[e + 6]; c7 = order[e + 7];
    }
    for (; e + 16 <= e1; e += 8) {
        int n0 = order[e + 8],  n1 = order[e + 9],  n2 = order[e + 10], n3 = order[e + 11];
        int n4 = order[e + 12], n5 = order[e + 13], n6 = order[e + 14], n7 = order[e + 15];
        ushort4 u0 = xv[(size_t)c0 * 32 + lane32];
        ushort4 u1 = xv[(size_t)c1 * 32 + lane32];
        ushort4 u2 = xv[(size_t)c2 * 32 + lane32];
        ushort4 u3 = xv[(size_t)c3 * 32 + lane32];
        ushort4 u4 = xv[(size_t)c4 * 32 + lane32];
        ushort4 u5 = xv[(size_t)c5 * 32 + lane32];
        ushort4 u6 = xv[(size_t)c6 * 32 + lane32];
        ushort4 u7 = xv[(size_t)c7 * 32 + lane32];
        float4 v0 = bf2f4(u0), v1 = bf2f4(u1), v2 = bf2f4(u2), v3 = bf2f4(u3);
        float4 v4 = bf2f4(u4), v5 = bf2f4(u5), v6 = bf2f4(u6), v7 = bf2f4(u7);
        a0.x += v0.x; a0.y += v0.y; a0.z += v0.z; a0.w += v0.w;
        a1.x += v1.x; a1.y += v1.y; a1.z += v1.z; a1.w += v1.w;
        a2.x += v2.x; a2.y += v2.y; a2.z += v2.z; a2.w += v2.w;
        a3.x += v3.x; a3.y += v3.y; a3.z += v3.z; a3.w += v3.w;
        a0.x += v4.x; a0.y += v4.y; a0.z += v4.z; a0.w += v4.w;
        a1.x += v5.x; a1.y += v5.y; a1.z += v5.z; a1.w += v5.w;
        a2.x += v6.x; a2.y += v6.y; a2.z += v6.z; a2.w += v6.w;
        a3.x += v7.x; a3.y += v7.y; a3.z += v7.z; a3.w += v7.w;
        c0 = n0; c1 = n1; c2 = n2; c3 = n3; c4 = n4; c5 = n5; c6 = n6; c7 = n7;
    }
    if (have && e + 8 <= e1) {
        ushort4 u0 = xv[(size_t)c0 * 32 + lane32];
        ushort4 u1 = xv[(size_t)c1 * 32 + lane32];
        ushort4 u2 = xv[(size_t)c2 * 32 + lane32];
        ushort4 u3 = xv[(size_t)c3 * 32 + lane32];
        ushort4 u4 = xv[(size_t)c4 * 32 + lane32];
        ushort4 u5 = xv[(size_t)c5 * 32 + lane32];
        ushort4 u6 = xv[(size_t)c6 * 32 + lane32];
        ushort4 u7 = xv[(size_t)c7 * 32 + lane32];
        float4 v0 = bf2f4(u0), v1 = bf2f4(u1), v2 = bf2f4(u2), v3 = bf2f4(u3);
        float4 v4 = bf2f4(u4), v5 = bf2f4(u5), v6 = bf2f4(u6), v7 = bf2f4(u7);
        a0.x += v0.x; a0.y += v0.y; a0.z += v0.z; a0.w += v0.w;
        a1.x += v1.x; a1.y += v1.y; a1.z += v1.z; a1.w += v1.w;
        a2.x += v2.x; a2.y += v2.y; a2.z += v2.z; a2.w += v2.w;
        a3.x += v3.x; a3.y += v3.y; a3.z += v3.z; a3.w += v3.w;
        a0.x += v4.x; a0.y += v4.y; a0.z += v4.z; a0.w += v4.w;
        a1.x += v5.x; a1.y += v5.y; a1.z += v5.z; a1.w += v5.w;
        a2.x += v6.x; a2.y += v6.y; a2.z += v6.z; a2.w += v6.w;
        a3.x += v7.x; a3.y += v7.y; a3.z += v7.z; a3.w += v7.w;
        e += 8;
    }
    for (; e + 4 <= e1; e += 4) {
        int s0 = order[e], s1 = order[e + 1], s2 = order[e + 2], s3 = order[e + 3];
        float4 v0 = bf2f4(xv[(size_t)s0 * 32 + lane32]);
        float4 v1 = bf2f4(xv[(size_t)s1 * 32 + lane32]);
        float4 v2 = bf2f4(xv[(size_t)s2 * 32 + lane32]);
        float4 v3 = bf2f4(xv[(size_t)s3 * 32 + lane32]);
        a0.x += v0.x; a0.y += v0.y; a0.z += v0.z; a0.w += v0.w;
        a1.x += v1.x; a1.y += v1.y; a1.z += v1.z; a1.w += v1.w;
        a2.x += v2.x; a2.y += v2.y; a2.z += v2.z; a2.w += v2.w;
        a3.x += v3.x; a3.y += v3.y; a3.z += v3.z; a3.w += v3.w;
    }
    for (; e < e1; ++e) {
        float4 v = bf2f4(xv[(size_t)order[e] * 32 + lane32]);
        a1.x += v.x; a1.y += v.y; a1.z += v.z; a1.w += v.w;
    }
    float4 t;
    t.x = (a0.x + a1.x) + (a2.x + a3.x);
    t.y = (a0.y + a1.y) + (a2.y + a3.y);
    t.z = (a0.z + a1.z) + (a2.z + a3.z);
    t.w = (a0.w + a1.w) + (a2.w + a3.w);
    ushort4 o;
    o.x = f2bf(t.x); o.y = f2bf(t.y); o.z = f2bf(t.z); o.w = f2bf(t.w);
    ((ushort4*)A1)[(size_t)node * 32 + lane32] = o;
}

// ---------------- fused GEMM1 -> BN -> GEMM2 -> GEMM3 (2 grid barriers) ----------------
// Phase A: GEMM1 (A1 @ W1, 128x256 tile, double-buffered staging), BN partials
//          written to global; accumulator kept in registers across the barriers.
// Phase B: blocks 0..255 reduce partials -> scale/shift (exact bn_reduce body).
// Phase C: BN+ReLU applied in-register, h1 tile staged in LDS (never hits HBM),
//          GEMM2 with B-fragments read directly from L2-resident W2t, then GEMM3.
// LDS = 33792 shorts (66 KiB): phase-A staging (30720) < h1t/h2t [128][264].
__global__ __launch_bounds__(512, 4) void mlp_kernel(
    const unsigned short* __restrict__ A1, const unsigned short* __restrict__ W1t,
    const float* __restrict__ b1,
    const float* __restrict__ gamma, const float* __restrict__ beta,
    const unsigned short* __restrict__ W2t, const float* __restrict__ b2,
    const unsigned short* __restrict__ Wlt, const float* __restrict__ blin,
    float* __restrict__ partials, float* __restrict__ scale, float* __restrict__ shift,
    int* __restrict__ bar, float* __restrict__ out, int M, int nB) {
    constexpr int S = 4;
    constexpr int PA = 40, PB = 40, PH = 264;
    constexpr int STAGE = 128 * PA + 256 * PB;        // 15360 shorts per buffer
    __shared__ __align__(16) unsigned short lds[128 * PH];  // 66 KiB

    int tid = threadIdx.x;
    int wave = tid >> 6, lane = tid & 63;
    int wm = wave >> 2, wn = wave & 3;
    int l15 = lane & 15, q = lane >> 4;
    long row0 = (long)blockIdx.x * 128;

    // ---- Phase A: GEMM1 ----
    int am = tid >> 2, ac = tid & 3;
    bf16x8 ar, br[2];
    auto loadAB = [&](int s) {
        ar = *(const bf16x8*)(A1 + (row0 + am) * F_IN + s * 32 + ac * 8);
#pragma unroll
        for (int i = 0; i < 2; ++i) {
            int ch = tid + i * 512;
            int m = ch >> 2, c = ch & 3;
            br[i] = *(const bf16x8*)(W1t + m * F_IN + s * 32 + c * 8);
        }
    };
    auto writeAB = [&](int buf) {
        unsigned short* As = lds + buf * STAGE;
        unsigned short* Bs = As + 128 * PA;
        *(bf16x8*)(&As[am * PA + ac * 8]) = ar;
#pragma unroll
        for (int i = 0; i < 2; ++i) {
            int ch = tid + i * 512;
            int m = ch >> 2, c = ch & 3;
            *(bf16x8*)(&Bs[m * PB + c * 8]) = br[i];
        }
    };

    f32x4 acc[4][4] = {};
    loadAB(0);
    writeAB(0);
#pragma unroll
    for (int s = 0; s < S; ++s) {
        if (s + 1 < S) loadAB(s + 1);
        __syncthreads();
        const unsigned short* As = lds + (s & 1) * STAGE;
        const unsigned short* Bs = As + 128 * PA;
        bf16x8 af[4], bfr[4];
#pragma unroll
        for (int mt = 0; mt < 4; ++mt)
            af[mt] = *(const bf16x8*)(&As[(wm * 64 + mt * 16 + l15) * PA + q * 8]);
#pragma unroll
        for (int nt = 0; nt < 4; ++nt)
            bfr[nt] = *(const bf16x8*)(&Bs[(wn * 64 + nt * 16 + l15) * PB + q * 8]);
#pragma unroll
        for (int mt = 0; mt < 4; ++mt)
#pragma unroll
            for (int nt = 0; nt < 4; ++nt)
                acc[mt][nt] = __builtin_amdgcn_mfma_f32_16x16x32_bf16(
                    af[mt], bfr[nt], acc[mt][nt], 0, 0, 0);
        if (s + 1 < S) writeAB((s + 1) & 1);
    }

    // BN partials from in-register acc (2 partial-rows per block)
#pragma unroll
    for (int nt = 0; nt < 4; ++nt) {
        int col = wn * 64 + nt * 16 + l15;
        float b = b1[col];
        float s = 0.f, ss = 0.f;
#pragma unroll
        for (int mt = 0; mt < 4; ++mt) {
#pragma unroll
            for (int r = 0; r < 4; ++r) {
                long row = row0 + wm * 64 + mt * 16 + q * 4 + r;
                float v = acc[mt][nt][r] + b;
                if (row < M) { s += v; ss += v * v; }
            }
        }
        s += __shfl_xor(s, 16, 64);  s += __shfl_xor(s, 32, 64);
        ss += __shfl_xor(ss, 16, 64); ss += __shfl_xor(ss, 32, 64);
        if (lane < 16) {
            long pr = (long)blockIdx.x * 2 + wm;
            partials[pr * 512 + col] = s;
            partials[pr * 512 + 256 + col] = ss;
        }
    }

    grid_barrier(bar, bar + 1, nB);

    // ---- Phase B: blocks 0..255 reduce one channel each (exact bn_reduce body) ----
    if (blockIdx.x < DIM_H) {
        float* ls = (float*)lds;
        float* lss = ls + 256;
        int c = blockIdx.x;
        int R = 2 * nB;
        float s = 0.f, ss = 0.f;
        if (tid < 256) {
            for (int r = tid; r < R; r += 256) {
                s += partials[(long)r * 512 + c];
                ss += partials[(long)r * 512 + 256 + c];
            }
            ls[tid] = s; lss[tid] = ss;
        }
        __syncthreads();
        for (int o = 128; o > 0; o >>= 1) {
            if (tid < o) { ls[tid] += ls[tid + o]; lss[tid] += lss[tid + o]; }
            __syncthreads();
        }
        if (tid == 0) {
            float inv = 1.0f / (float)M;
            float mean = ls[0] * inv;
            float var = lss[0] * inv - mean * mean;
            float sc = gamma[c] * rsqrtf(var + BN_EPS);
            scale[c] = sc;
            shift[c] = beta[c] - mean * sc;
        }
    }

    grid_barrier(bar + 2, bar + 3, nB);

    // ---- Phase C: BN+ReLU in-register -> h1t LDS; GEMM2 (B from global); GEMM3 ----
    unsigned short* h1t = lds;
#pragma unroll
    for (int nt = 0; nt < 4; ++nt) {
        int col = wn * 64 + nt * 16 + l15;
        float b = b1[col];
        float sc = scale[col], sh = shift[col];
#pragma unroll
        for (int mt = 0; mt < 4; ++mt) {
#pragma unroll
            for (int r = 0; r < 4; ++r) {
                int rowL = wm * 64 + mt * 16 + q * 4 + r;
                float v = acc[mt][nt][r] + b;
                v = fmaxf(v * sc + sh, 0.f);
                h1t[rowL * PH + col] = f2bf(v);
            }
        }
    }
    __syncthreads();

    f32x4 acc2[4][4] = {};
#pragma unroll
    for (int s = 0; s < 8; ++s) {
        bf16x8 af[4], bfr[4];
#pragma unroll
        for (int mt = 0; mt < 4; ++mt)
            af[mt] = *(const bf16x8*)(&h1t[(wm * 64 + mt * 16 + l15) * PH + s * 32 + q * 8]);
#pragma unroll
        for (int nt = 0; nt < 4; ++nt)
            bfr[nt] = *(const bf16x8*)(W2t + (wn * 64 + nt * 16 + l15) * DIM_H + s * 32 + q * 8);
#pragma unroll
        for (int mt = 0; mt < 4; ++mt)
#pragma unroll
            for (int nt = 0; nt < 4; ++nt)
                acc2[mt][nt] = __builtin_amdgcn_mfma_f32_16x16x32_bf16(
                    af[mt], bfr[nt], acc2[mt][nt], 0, 0, 0);
    }
    __syncthreads();  // h1t consumed; alias h2t

    unsigned short* h2t = lds;
#pragma unroll
    for (int nt = 0; nt < 4; ++nt) {
        int colL = wn * 64 + nt * 16 + l15;
        float b = b2[colL];
#pragma unroll
        for (int mt = 0; mt < 4; ++mt)
#pragma unroll
            for (int r = 0; r < 4; ++r) {
                int rowL = wm * 64 + mt * 16 + q * 4 + r;
                h2t[rowL * PH + colL] = f2bf(fmaxf(acc2[mt][nt][r] + b, 0.f));
            }
    }
    __syncthreads();

    f32x4 acc3[3] = {};
#pragma unroll
    for (int s = 0; s < 8; ++s) {
        bf16x8 a3 = *(const bf16x8*)(&h2t[(wave * 16 + l15) * PH + s * 32 + q * 8]);
#pragma unroll
        for (int nt = 0; nt < 3; ++nt) {
            bf16x8 b3 = *(const bf16x8*)(Wlt + (nt * 16 + l15) * 256 + s * 32 + q * 8);
            acc3[nt] = __builtin_amdgcn_mfma_f32_16x16x32_bf16(a3, b3, acc3[nt], 0, 0, 0);
        }
    }
#pragma unroll
    for (int nt = 0; nt < 3; ++nt) {
        int col = nt * 16 + l15;
        if (col < N_CLASSES) {
            float b = blin[col];
#pragma unroll
            for (int r = 0; r < 4; ++r) {
                long row = row0 + wave * 16 + q * 4 + r;
                if (row < M) out[row * N_CLASSES + col] = acc3[nt][r] + b;
            }
        }
    }
}

extern "C" void kernel_launch(void* const* d_in, const int* in_sizes, int n_in,
                              void* d_out, int out_size, void* d_ws, size_t ws_size,
                              hipStream_t stream) {
    const float* x     = (const float*)d_in[0];
    const int*   ei    = (const int*)d_in[1];
    const float* W1    = (const float*)d_in[2];
    const float* b1    = (const float*)d_in[3];
    const float* gamma = (const float*)d_in[4];
    const float* beta  = (const float*)d_in[5];
    const float* W2    = (const float*)d_in[6];
    const float* b2    = (const float*)d_in[7];
    const float* Wlin  = (const float*)d_in[8];
    const float* blin  = (const float*)d_in[9];
    float* out = (float*)d_out;

    int M  = in_sizes[0] / F_IN;  // 50000
    int nE = in_sizes[1] / 2;     // 600000
    const int* srcIdx = ei;
    const int* dstIdx = ei + nE;
    int nB = (M + 255) / 256;     // 196 (scan blocks)
    int g128 = (M + 127) / 128;   // 391 (GEMM tiles / mlp grid)
    int XQ = M * 32;
    int ZQ = (M + 4) / 4;         // hist + bar[4], in int4 units

    unsigned short* xb    = (unsigned short*)d_ws;                     // M_PAD*128
    unsigned short* A1bf  = xb + (size_t)M_PAD * F_IN;                 // M_PAD*128
    unsigned short* W1t   = A1bf + (size_t)M_PAD * F_IN;               // 256*128
    unsigned short* W2t   = W1t + DIM_H * F_IN;                        // 256*256
    unsigned short* Wlt   = W2t + DIM_H * DIM_H;                       // 64*256
    float*          partials = (float*)(Wlt + 64 * DIM_H);             // 2*g128*512
    float*          scale = partials + (size_t)800 * 512;              // 256
    float*          shift = scale + DIM_H;                             // 256
    int*            hist  = (int*)(shift + DIM_H);                     // M
    int*            bar   = hist + M;                                  // 4 (zeroed with hist)
    int*            cursor= bar + 4;                                   // M
    int*            start = cursor + M;                                // M+1
    int*            order = start + (M + 1);                           // nE

    int tB = 256;
    prep_kernel<<<(XQ + 114688 + ZQ + 255) / 256, 256, 0, stream>>>(
        x, xb, W1, W2, Wlin, W1t, W2t, Wlt, hist, XQ, ZQ);
    hist_kernel<<<(nE + tB - 1) / tB, tB, 0, stream>>>(dstIdx, hist, nE);
    scan_kernel<<<nB, 256, 0, stream>>>(hist, start, cursor, M, nE);
    fill_kernel<<<(nE + tB - 1) / tB, tB, 0, stream>>>(srcIdx, dstIdx, cursor, order, nE);

    // standalone max-occupancy gather
    gather_kernel<<<(M + 7) / 8, 256, 0, stream>>>(xb, order, start, A1bf, M);
    // fused GEMM1 -> BN -> GEMM2 -> GEMM3 (grid barriers; h1/h2 never leave LDS)
    mlp_kernel<<<g128, 512, 0, stream>>>(A1bf, W1t, b1, gamma, beta, W2t, b2,
                                         Wlt, blin, partials, scale, shift,
                                         bar, out, M, g128);
}

// Round 6
// 263.504 us; speedup vs baseline: 1.3347x; 1.3347x over previous
//
#include <hip/hip_runtime.h>

#define F_IN 128
#define DIM_H 256
#define N_CLASSES 40
#define BN_EPS 1e-5f
#define M_PAD 50176

typedef short bf16x8 __attribute__((ext_vector_type(8)));
typedef float f32x4 __attribute__((ext_vector_type(4)));

__device__ __forceinline__ unsigned short f2bf(float f) {
    union { float f; unsigned u; } v; v.f = f;
    unsigned r = v.u + 0x7fff + ((v.u >> 16) & 1);  // RNE
    return (unsigned short)(r >> 16);
}
__device__ __forceinline__ float bf2f(unsigned short u) {
    union { unsigned u; float f; } v; v.u = ((unsigned)u) << 16;
    return v.f;
}
__device__ __forceinline__ float4 bf2f4(ushort4 u) {
    return make_float4(bf2f(u.x), bf2f(u.y), bf2f(u.z), bf2f(u.w));
}

// ---------------- Phase A: histogram of dst ----------------
__global__ void hist_kernel(const int* __restrict__ dst, int* __restrict__ hist, int nE) {
    int e = blockIdx.x * blockDim.x + threadIdx.x;
    if (e >= nE) return;
    atomicAdd(&hist[dst[e]], 1);
}

// ---------------- Phase B: single-kernel scan (fused blocks+final) ----------------
// Each block computes its global prefix by directly summing hist[0..base).
// Also seeds cursor[i] = start[i] so fill_kernel needs no start[] read.
__global__ void scan_kernel(const int* __restrict__ hist,
                            int* __restrict__ start, int* __restrict__ cursor,
                            int M, int nE) {
    __shared__ int lds[256];
    __shared__ int s_prefix;
    int t = threadIdx.x;
    int base = blockIdx.x * 256;
    int s = 0;
    for (int i = t; i < base; i += 256) s += hist[i];
    lds[t] = s;
    __syncthreads();
    for (int o = 128; o > 0; o >>= 1) {
        if (t < o) lds[t] += lds[t + o];
        __syncthreads();
    }
    if (t == 0) s_prefix = lds[0];
    __syncthreads();
    int prefix = s_prefix;
    __syncthreads();           // lds reuse below
    int i = base + t;
    int orig = (i < M) ? hist[i] : 0;
    lds[t] = orig;
    __syncthreads();
    for (int o = 1; o < 256; o <<= 1) {
        int v = (t >= o) ? lds[t - o] : 0;
        __syncthreads();
        lds[t] += v;
        __syncthreads();
    }
    if (i < M) {
        int v = prefix + lds[t] - orig;
        start[i] = v;
        cursor[i] = v;
    }
    if (blockIdx.x == 0 && t == 0) start[M] = nE;
}

// ---------------- Phase C: bucket-fill src indices ----------------
__global__ void fill_kernel(const int* __restrict__ src, const int* __restrict__ dst,
                            int* __restrict__ cursor,
                            int* __restrict__ order, int nE) {
    int e = blockIdx.x * blockDim.x + threadIdx.x;
    if (e >= nE) return;
    int pos = atomicAdd(&cursor[dst[e]], 1);
    order[pos] = src[e];
}

// ---------------- prep: xb = bf16(x), weight transposes, hist+bnsum zeroing ----------------
__global__ void prep_kernel(const float* __restrict__ x, unsigned short* __restrict__ xb,
                            const float* __restrict__ W1, const float* __restrict__ W2,
                            const float* __restrict__ Wl,
                            unsigned short* __restrict__ W1t,
                            unsigned short* __restrict__ W2t,
                            unsigned short* __restrict__ Wlt,
                            int* __restrict__ histz, int XQ, int ZQ) {
    int idx = blockIdx.x * 256 + threadIdx.x;
    if (idx < XQ) {
        float4 v = ((const float4*)x)[idx];
        ushort4 o;
        o.x = f2bf(v.x); o.y = f2bf(v.y); o.z = f2bf(v.z); o.w = f2bf(v.w);
        ((ushort4*)xb)[idx] = o;
        return;
    }
    int j = idx - XQ;
    if (j < 32768) {                    // W1t: [n=256][k=128]
        int n = j >> 7, k = j & 127;
        W1t[j] = f2bf(W1[k * DIM_H + n]);
    } else if (j < 32768 + 65536) {     // W2t: [n=256][k=256]
        int i = j - 32768;
        int n = i >> 8, k = i & 255;
        W2t[i] = f2bf(W2[k * DIM_H + n]);
    } else if (j < 32768 + 65536 + 16384) {  // Wlt: [n=64][k=256]
        int i = j - 98304;
        int n = i >> 8, k = i & 255;
        Wlt[i] = f2bf((n < N_CLASSES) ? Wl[k * N_CLASSES + n] : 0.f);
    } else {
        int z = j - 114688;
        if (z >= 0 && z < ZQ) ((int4*)histz)[z] = make_int4(0, 0, 0, 0);
    }
}

// ---------------- standalone gather: A1 = bf16(x + agg) ----------------
// One half-wave per row, 8-deep independent loads. No LDS, tiny VGPR count
// -> max occupancy. Round-0 proven configuration (232.6 us total).
__global__ __launch_bounds__(256) void gather_kernel(
    const unsigned short* __restrict__ xb,
    const int* __restrict__ order, const int* __restrict__ start,
    unsigned short* __restrict__ A1, int M) {
    int node = blockIdx.x * 8 + (threadIdx.x >> 5);
    if (node >= M) return;
    int lane32 = threadIdx.x & 31;
    const ushort4* xv = (const ushort4*)xb;
    float4 a0 = bf2f4(xv[(size_t)node * 32 + lane32]);  // self term
    float4 a1 = make_float4(0.f, 0.f, 0.f, 0.f);
    float4 a2 = a1, a3 = a1;
    int e0 = start[node], e1 = start[node + 1];
    int e = e0;
    for (; e + 8 <= e1; e += 8) {
        int s0 = order[e],     s1 = order[e + 1], s2 = order[e + 2], s3 = order[e + 3];
        int s4 = order[e + 4], s5 = order[e + 5], s6 = order[e + 6], s7 = order[e + 7];
        ushort4 u0 = xv[(size_t)s0 * 32 + lane32];
        ushort4 u1 = xv[(size_t)s1 * 32 + lane32];
        ushort4 u2 = xv[(size_t)s2 * 32 + lane32];
        ushort4 u3 = xv[(size_t)s3 * 32 + lane32];
        ushort4 u4 = xv[(size_t)s4 * 32 + lane32];
        ushort4 u5 = xv[(size_t)s5 * 32 + lane32];
        ushort4 u6 = xv[(size_t)s6 * 32 + lane32];
        ushort4 u7 = xv[(size_t)s7 * 32 + lane32];
        float4 v0 = bf2f4(u0), v1 = bf2f4(u1), v2 = bf2f4(u2), v3 = bf2f4(u3);
        float4 v4 = bf2f4(u4), v5 = bf2f4(u5), v6 = bf2f4(u6), v7 = bf2f4(u7);
        a0.x += v0.x; a0.y += v0.y; a0.z += v0.z; a0.w += v0.w;
        a1.x += v1.x; a1.y += v1.y; a1.z += v1.z; a1.w += v1.w;
        a2.x += v2.x; a2.y += v2.y; a2.z += v2.z; a2.w += v2.w;
        a3.x += v3.x; a3.y += v3.y; a3.z += v3.z; a3.w += v3.w;
        a0.x += v4.x; a0.y += v4.y; a0.z += v4.z; a0.w += v4.w;
        a1.x += v5.x; a1.y += v5.y; a1.z += v5.z; a1.w += v5.w;
        a2.x += v6.x; a2.y += v6.y; a2.z += v6.z; a2.w += v6.w;
        a3.x += v7.x; a3.y += v7.y; a3.z += v7.z; a3.w += v7.w;
    }
    for (; e + 4 <= e1; e += 4) {
        int s0 = order[e], s1 = order[e + 1], s2 = order[e + 2], s3 = order[e + 3];
        float4 v0 = bf2f4(xv[(size_t)s0 * 32 + lane32]);
        float4 v1 = bf2f4(xv[(size_t)s1 * 32 + lane32]);
        float4 v2 = bf2f4(xv[(size_t)s2 * 32 + lane32]);
        float4 v3 = bf2f4(xv[(size_t)s3 * 32 + lane32]);
        a0.x += v0.x; a0.y += v0.y; a0.z += v0.z; a0.w += v0.w;
        a1.x += v1.x; a1.y += v1.y; a1.z += v1.z; a1.w += v1.w;
        a2.x += v2.x; a2.y += v2.y; a2.z += v2.z; a2.w += v2.w;
        a3.x += v3.x; a3.y += v3.y; a3.z += v3.z; a3.w += v3.w;
    }
    for (; e < e1; ++e) {
        float4 v = bf2f4(xv[(size_t)order[e] * 32 + lane32]);
        a1.x += v.x; a1.y += v.y; a1.z += v.z; a1.w += v.w;
    }
    float4 t;
    t.x = (a0.x + a1.x) + (a2.x + a3.x);
    t.y = (a0.y + a1.y) + (a2.y + a3.y);
    t.z = (a0.z + a1.z) + (a2.z + a3.z);
    t.w = (a0.w + a1.w) + (a2.w + a3.w);
    ushort4 o;
    o.x = f2bf(t.x); o.y = f2bf(t.y); o.z = f2bf(t.z); o.w = f2bf(t.w);
    ((ushort4*)A1)[(size_t)node * 32 + lane32] = o;
}

// ---------------- GEMM1: h1 = bf16(A1 @ W1 + b1) + BN sums via atomics ----------------
// 128x256 tile, 512 threads (2x4 waves), K=128 (4 steps), double-buffered staging.
// Epilogue: per-block BN sums reduced in-wave, then atomicAdd into the 512-float
// global accumulator (bn_reduce kernel eliminated; validated in round 1).
__global__ __launch_bounds__(512, 4) void gemm1_kernel(
    const unsigned short* __restrict__ A1, const unsigned short* __restrict__ W1t,
    const float* __restrict__ b1, unsigned short* __restrict__ h1,
    float* __restrict__ bnsum, int M) {
    constexpr int S = 4;
    constexpr int PA = 40, PB = 40, PH = 264;
    constexpr int STAGE = 128 * PA + 256 * PB;        // 15360 ushorts per buffer
    __shared__ __align__(16) unsigned short lds[128 * PH];  // 67.6 KB >= 2*STAGE
    unsigned short* h1t = lds;

    int tid = threadIdx.x;
    int wave = tid >> 6, lane = tid & 63;
    int wm = wave >> 2, wn = wave & 3;
    int l15 = lane & 15, q = lane >> 4;
    long row0 = (long)blockIdx.x * 128;

    int am = tid >> 2, ac = tid & 3;
    bf16x8 ar, br[2];
    auto loadAB = [&](int s) {
        ar = *(const bf16x8*)(A1 + (row0 + am) * F_IN + s * 32 + ac * 8);
#pragma unroll
        for (int i = 0; i < 2; ++i) {
            int ch = tid + i * 512;
            int m = ch >> 2, c = ch & 3;
            br[i] = *(const bf16x8*)(W1t + m * F_IN + s * 32 + c * 8);
        }
    };
    auto writeAB = [&](int buf) {
        unsigned short* As = lds + buf * STAGE;
        unsigned short* Bs = As + 128 * PA;
        *(bf16x8*)(&As[am * PA + ac * 8]) = ar;
#pragma unroll
        for (int i = 0; i < 2; ++i) {
            int ch = tid + i * 512;
            int m = ch >> 2, c = ch & 3;
            *(bf16x8*)(&Bs[m * PB + c * 8]) = br[i];
        }
    };

    f32x4 acc[4][4] = {};
    loadAB(0);
    writeAB(0);
#pragma unroll
    for (int s = 0; s < S; ++s) {
        if (s + 1 < S) loadAB(s + 1);
        __syncthreads();
        const unsigned short* As = lds + (s & 1) * STAGE;
        const unsigned short* Bs = As + 128 * PA;
        bf16x8 af[4], bfr[4];
#pragma unroll
        for (int mt = 0; mt < 4; ++mt)
            af[mt] = *(const bf16x8*)(&As[(wm * 64 + mt * 16 + l15) * PA + q * 8]);
#pragma unroll
        for (int nt = 0; nt < 4; ++nt)
            bfr[nt] = *(const bf16x8*)(&Bs[(wn * 64 + nt * 16 + l15) * PB + q * 8]);
#pragma unroll
        for (int mt = 0; mt < 4; ++mt)
#pragma unroll
            for (int nt = 0; nt < 4; ++nt)
                acc[mt][nt] = __builtin_amdgcn_mfma_f32_16x16x32_bf16(
                    af[mt], bfr[nt], acc[mt][nt], 0, 0, 0);
        if (s + 1 < S) writeAB((s + 1) & 1);
    }
    __syncthreads();  // staging reads done; alias h1t

    // ---- Epilogue: BN sums (atomic) + staged h1 tile ----
#pragma unroll
    for (int nt = 0; nt < 4; ++nt) {
        int col = wn * 64 + nt * 16 + l15;
        float b = b1[col];
        float s = 0.f, ss = 0.f;
#pragma unroll
        for (int mt = 0; mt < 4; ++mt) {
#pragma unroll
            for (int r = 0; r < 4; ++r) {
                long row = row0 + wm * 64 + mt * 16 + q * 4 + r;
                float v = acc[mt][nt][r] + b;
                if (row < M) { s += v; ss += v * v; }
                h1t[(wm * 64 + mt * 16 + q * 4 + r) * PH + col] = f2bf(v);
            }
        }
        s += __shfl_xor(s, 16, 64);  s += __shfl_xor(s, 32, 64);
        ss += __shfl_xor(ss, 16, 64); ss += __shfl_xor(ss, 32, 64);
        if (lane < 16) {
            atomicAdd(&bnsum[col], s);
            atomicAdd(&bnsum[DIM_H + col], ss);
        }
    }
    __syncthreads();
    {   // contiguous stores: thread t -> row t>>2, 64-col segment (t&3)*64
        int srow = tid >> 2, scol = (tid & 3) * 64;
        unsigned short* dst = h1 + (row0 + srow) * DIM_H + scol;
        const unsigned short* srcp = &h1t[srow * PH + scol];
#pragma unroll
        for (int j = 0; j < 8; ++j)
            *(bf16x8*)(dst + j * 8) = *(const bf16x8*)(srcp + j * 8);
    }
}

// ---------------- fused GEMM2 + GEMM3 with BN-finalize prologue ----------------
__global__ __launch_bounds__(512, 4) void gemm23_kernel(
    const unsigned short* __restrict__ h1, const unsigned short* __restrict__ W2t,
    const float* __restrict__ b2,
    const float* __restrict__ bnsum,
    const float* __restrict__ gamma, const float* __restrict__ beta,
    const unsigned short* __restrict__ Wlt, const float* __restrict__ blin,
    float* __restrict__ out, int M) {
    constexpr int S = 8;
    constexpr int PA = 40, PB = 40, PH = 264;
    constexpr int STAGE = 128 * PA + 256 * PB;
    __shared__ __align__(16) unsigned short lds[128 * PH];
    __shared__ __align__(16) float s_scale[DIM_H];
    __shared__ __align__(16) float s_shift[DIM_H];
    unsigned short* h2t = lds;

    int tid = threadIdx.x;
    int wave = tid >> 6, lane = tid & 63;
    int wm = wave >> 2, wn = wave & 3;
    int l15 = lane & 15, q = lane >> 4;
    long row0 = (long)blockIdx.x * 128;

    // BN finalize: 256 threads compute per-channel scale/shift from the global sums
    if (tid < DIM_H) {
        float inv = 1.0f / (float)M;
        float mean = bnsum[tid] * inv;
        float var  = bnsum[DIM_H + tid] * inv - mean * mean;
        float sc = gamma[tid] * rsqrtf(var + BN_EPS);
        s_scale[tid] = sc;
        s_shift[tid] = beta[tid] - mean * sc;
    }

    int am = tid >> 2, ac = tid & 3;
    bf16x8 ar, br[2];
    auto loadAB = [&](int s) {
        ar = *(const bf16x8*)(h1 + (row0 + am) * DIM_H + s * 32 + ac * 8);
#pragma unroll
        for (int i = 0; i < 2; ++i) {
            int ch = tid + i * 512;
            int m = ch >> 2, c = ch & 3;
            br[i] = *(const bf16x8*)(W2t + m * DIM_H + s * 32 + c * 8);
        }
    };
    auto writeAB = [&](int s, int buf) {
        unsigned short* As = lds + buf * STAGE;
        unsigned short* Bs = As + 128 * PA;
        {
            int kb = s * 32 + ac * 8;
            float4 sc0 = *(const float4*)(s_scale + kb);
            float4 sc1 = *(const float4*)(s_scale + kb + 4);
            float4 sh0 = *(const float4*)(s_shift + kb);
            float4 sh1 = *(const float4*)(s_shift + kb + 4);
            float scv[8] = {sc0.x, sc0.y, sc0.z, sc0.w, sc1.x, sc1.y, sc1.z, sc1.w};
            float shv[8] = {sh0.x, sh0.y, sh0.z, sh0.w, sh1.x, sh1.y, sh1.z, sh1.w};
            bf16x8 v = ar;
#pragma unroll
            for (int j = 0; j < 8; ++j) {
                float f = bf2f((unsigned short)v[j]);
                f = fmaxf(f * scv[j] + shv[j], 0.f);
                v[j] = (short)f2bf(f);
            }
            *(bf16x8*)(&As[am * PA + ac * 8]) = v;
        }
#pragma unroll
        for (int i = 0; i < 2; ++i) {
            int ch = tid + i * 512;
            int m = ch >> 2, c = ch & 3;
            *(bf16x8*)(&Bs[m * PB + c * 8]) = br[i];
        }
    };

    f32x4 acc[4][4] = {};
    loadAB(0);
    __syncthreads();   // s_scale/s_shift ready before first writeAB
    writeAB(0, 0);
#pragma unroll
    for (int s = 0; s < S; ++s) {
        if (s + 1 < S) loadAB(s + 1);
        __syncthreads();
        const unsigned short* As = lds + (s & 1) * STAGE;
        const unsigned short* Bs = As + 128 * PA;
        bf16x8 af[4], bfr[4];
#pragma unroll
        for (int mt = 0; mt < 4; ++mt)
            af[mt] = *(const bf16x8*)(&As[(wm * 64 + mt * 16 + l15) * PA + q * 8]);
#pragma unroll
        for (int nt = 0; nt < 4; ++nt)
            bfr[nt] = *(const bf16x8*)(&Bs[(wn * 64 + nt * 16 + l15) * PB + q * 8]);
#pragma unroll
        for (int mt = 0; mt < 4; ++mt)
#pragma unroll
            for (int nt = 0; nt < 4; ++nt)
                acc[mt][nt] = __builtin_amdgcn_mfma_f32_16x16x32_bf16(
                    af[mt], bfr[nt], acc[mt][nt], 0, 0, 0);
        if (s + 1 < S) writeAB(s + 1, (s + 1) & 1);
    }
    __syncthreads();

#pragma unroll
    for (int nt = 0; nt < 4; ++nt) {
        int colL = wn * 64 + nt * 16 + l15;
        float b = b2[colL];
#pragma unroll
        for (int mt = 0; mt < 4; ++mt)
#pragma unroll
            for (int r = 0; r < 4; ++r) {
                int rowL = wm * 64 + mt * 16 + q * 4 + r;
                h2t[rowL * PH + colL] = f2bf(fmaxf(acc[mt][nt][r] + b, 0.f));
            }
    }
    __syncthreads();

    f32x4 acc3[3] = {};
#pragma unroll
    for (int s = 0; s < 8; ++s) {
        bf16x8 a3 = *(const bf16x8*)(&h2t[(wave * 16 + l15) * PH + s * 32 + q * 8]);
#pragma unroll
        for (int nt = 0; nt < 3; ++nt) {
            bf16x8 b3 = *(const bf16x8*)(Wlt + (nt * 16 + l15) * 256 + s * 32 + q * 8);
            acc3[nt] = __builtin_amdgcn_mfma_f32_16x16x32_bf16(a3, b3, acc3[nt], 0, 0, 0);
        }
    }
#pragma unroll
    for (int nt = 0; nt < 3; ++nt) {
        int col = nt * 16 + l15;
        if (col < N_CLASSES) {
            float b = blin[col];
#pragma unroll
            for (int r = 0; r < 4; ++r) {
                long row = row0 + wave * 16 + q * 4 + r;
                if (row < M) out[row * N_CLASSES + col] = acc3[nt][r] + b;
            }
        }
    }
}

extern "C" void kernel_launch(void* const* d_in, const int* in_sizes, int n_in,
                              void* d_out, int out_size, void* d_ws, size_t ws_size,
                              hipStream_t stream) {
    const float* x     = (const float*)d_in[0];
    const int*   ei    = (const int*)d_in[1];
    const float* W1    = (const float*)d_in[2];
    const float* b1    = (const float*)d_in[3];
    const float* gamma = (const float*)d_in[4];
    const float* beta  = (const float*)d_in[5];
    const float* W2    = (const float*)d_in[6];
    const float* b2    = (const float*)d_in[7];
    const float* Wlin  = (const float*)d_in[8];
    const float* blin  = (const float*)d_in[9];
    float* out = (float*)d_out;

    int M  = in_sizes[0] / F_IN;  // 50000
    int nE = in_sizes[1] / 2;     // 600000
    const int* srcIdx = ei;
    const int* dstIdx = ei + nE;
    int nB = (M + 255) / 256;     // 196 (scan blocks)
    int g128 = (M + 127) / 128;   // 391 (GEMM tiles)
    int XQ = M * 32;
    int ZQ = (M + 2 * DIM_H) / 4; // hist + bnsum, in int4 units

    unsigned short* h1bf  = (unsigned short*)d_ws;                     // M_PAD*256
    unsigned short* xb    = h1bf + (size_t)M_PAD * DIM_H;              // M_PAD*128
    unsigned short* A1bf  = xb + (size_t)M_PAD * F_IN;                 // M_PAD*128
    unsigned short* W1t   = A1bf + (size_t)M_PAD * F_IN;               // 256*128
    unsigned short* W2t   = W1t + DIM_H * F_IN;                        // 256*256
    unsigned short* Wlt   = W2t + DIM_H * DIM_H;                       // 64*256
    int*            hist  = (int*)(Wlt + 64 * DIM_H);                  // M
    float*          bnsum = (float*)(hist + M);                        // 512 (zeroed with hist)
    int*            cursor= (int*)(bnsum + 2 * DIM_H);                 // M (seeded by scan)
    int*            start = cursor + M;                                // M+1
    int*            order = start + (M + 1);                           // nE

    int tB = 256;
    prep_kernel<<<(XQ + 114688 + ZQ + 255) / 256, 256, 0, stream>>>(
        x, xb, W1, W2, Wlin, W1t, W2t, Wlt, hist, XQ, ZQ);
    hist_kernel<<<(nE + tB - 1) / tB, tB, 0, stream>>>(dstIdx, hist, nE);
    scan_kernel<<<nB, 256, 0, stream>>>(hist, start, cursor, M, nE);
    fill_kernel<<<(nE + tB - 1) / tB, tB, 0, stream>>>(srcIdx, dstIdx, cursor, order, nE);

    // standalone max-occupancy gather (round-0 proven form)
    gather_kernel<<<(M + 7) / 8, 256, 0, stream>>>(xb, order, start, A1bf, M);
    // GEMM1 + atomic BN sums
    gemm1_kernel<<<g128, 512, 0, stream>>>(A1bf, W1t, b1, h1bf, bnsum, M);
    // fused BN-finalize + GEMM2 + GEMM3
    gemm23_kernel<<<g128, 512, 0, stream>>>(h1bf, W2t, b2, bnsum, gamma, beta,
                                            Wlt, blin, out, M);
}

// Round 7
// 253.872 us; speedup vs baseline: 1.3853x; 1.0379x over previous
//
#include <hip/hip_runtime.h>

#define F_IN 128
#define DIM_H 256
#define N_CLASSES 40
#define BN_EPS 1e-5f
#define M_PAD 50176

typedef short bf16x8 __attribute__((ext_vector_type(8)));
typedef float f32x4 __attribute__((ext_vector_type(4)));

__device__ __forceinline__ unsigned short f2bf(float f) {
    union { float f; unsigned u; } v; v.f = f;
    unsigned r = v.u + 0x7fff + ((v.u >> 16) & 1);  // RNE
    return (unsigned short)(r >> 16);
}
__device__ __forceinline__ float bf2f(unsigned short u) {
    union { unsigned u; float f; } v; v.u = ((unsigned)u) << 16;
    return v.f;
}
__device__ __forceinline__ float4 bf2f4(ushort4 u) {
    return make_float4(bf2f(u.x), bf2f(u.y), bf2f(u.z), bf2f(u.w));
}

// ---------------- Phase A: histogram of dst ----------------
__global__ void hist_kernel(const int* __restrict__ dst, int* __restrict__ hist, int nE) {
    int e = blockIdx.x * blockDim.x + threadIdx.x;
    if (e >= nE) return;
    atomicAdd(&hist[dst[e]], 1);
}

// ---------------- Phase B: single-kernel scan (fused; seeds cursor) ----------------
// Each block computes its global prefix by directly summing hist[0..base)
// (~20 MB of L2 reads total — ~3 us). Seeds cursor[i] = start[i] so
// fill_kernel needs no start[] read. Proven correct in rounds 2/6.
__global__ void scan_kernel(const int* __restrict__ hist,
                            int* __restrict__ start, int* __restrict__ cursor,
                            int M, int nE) {
    __shared__ int lds[256];
    __shared__ int s_prefix;
    int t = threadIdx.x;
    int base = blockIdx.x * 256;
    int s = 0;
    for (int i = t; i < base; i += 256) s += hist[i];
    lds[t] = s;
    __syncthreads();
    for (int o = 128; o > 0; o >>= 1) {
        if (t < o) lds[t] += lds[t + o];
        __syncthreads();
    }
    if (t == 0) s_prefix = lds[0];
    __syncthreads();
    int prefix = s_prefix;
    __syncthreads();           // lds reuse below
    int i = base + t;
    int orig = (i < M) ? hist[i] : 0;
    lds[t] = orig;
    __syncthreads();
    for (int o = 1; o < 256; o <<= 1) {
        int v = (t >= o) ? lds[t - o] : 0;
        __syncthreads();
        lds[t] += v;
        __syncthreads();
    }
    if (i < M) {
        int v = prefix + lds[t] - orig;
        start[i] = v;
        cursor[i] = v;
    }
    if (blockIdx.x == 0 && t == 0) start[M] = nE;
}

// ---------------- Phase C: bucket-fill src indices ----------------
__global__ void fill_kernel(const int* __restrict__ src, const int* __restrict__ dst,
                            int* __restrict__ cursor,
                            int* __restrict__ order, int nE) {
    int e = blockIdx.x * blockDim.x + threadIdx.x;
    if (e >= nE) return;
    int pos = atomicAdd(&cursor[dst[e]], 1);
    order[pos] = src[e];
}

// ---------------- prep: xb = bf16(x), weight transposes, hist zeroing ----------------
__global__ void prep_kernel(const float* __restrict__ x, unsigned short* __restrict__ xb,
                            const float* __restrict__ W1, const float* __restrict__ W2,
                            const float* __restrict__ Wl,
                            unsigned short* __restrict__ W1t,
                            unsigned short* __restrict__ W2t,
                            unsigned short* __restrict__ Wlt,
                            int* __restrict__ histz, int XQ, int ZQ) {
    int idx = blockIdx.x * 256 + threadIdx.x;
    if (idx < XQ) {
        float4 v = ((const float4*)x)[idx];
        ushort4 o;
        o.x = f2bf(v.x); o.y = f2bf(v.y); o.z = f2bf(v.z); o.w = f2bf(v.w);
        ((ushort4*)xb)[idx] = o;
        return;
    }
    int j = idx - XQ;
    if (j < 32768) {                    // W1t: [n=256][k=128]
        int n = j >> 7, k = j & 127;
        W1t[j] = f2bf(W1[k * DIM_H + n]);
    } else if (j < 32768 + 65536) {     // W2t: [n=256][k=256]
        int i = j - 32768;
        int n = i >> 8, k = i & 255;
        W2t[i] = f2bf(W2[k * DIM_H + n]);
    } else if (j < 32768 + 65536 + 16384) {  // Wlt: [n=64][k=256]
        int i = j - 98304;
        int n = i >> 8, k = i & 255;
        Wlt[i] = f2bf((n < N_CLASSES) ? Wl[k * N_CLASSES + n] : 0.f);
    } else {
        int z = j - 114688;
        if (z >= 0 && z < ZQ) ((int4*)histz)[z] = make_int4(0, 0, 0, 0);
    }
}

// ---------------- BN reduce ----------------
__global__ void bn_reduce_kernel(const float* __restrict__ partials, int R,
                                 const float* __restrict__ gamma,
                                 const float* __restrict__ beta,
                                 float* __restrict__ scale,
                                 float* __restrict__ shift, int M) {
    __shared__ float ls[256], lss[256];
    int c = blockIdx.x, t = threadIdx.x;
    float s = 0.f, ss = 0.f;
    for (int r = t; r < R; r += 256) {
        s += partials[(long)r * 512 + c];
        ss += partials[(long)r * 512 + 256 + c];
    }
    ls[t] = s; lss[t] = ss;
    __syncthreads();
    for (int o = 128; o > 0; o >>= 1) {
        if (t < o) { ls[t] += ls[t + o]; lss[t] += lss[t + o]; }
        __syncthreads();
    }
    if (t == 0) {
        float inv = 1.0f / (float)M;
        float mean = ls[0] * inv;
        float var = lss[0] * inv - mean * mean;
        float sc = gamma[c] * rsqrtf(var + BN_EPS);
        scale[c] = sc;
        shift[c] = beta[c] - mean * sc;
    }
}

// ---------------- standalone gather: A1 = bf16(x + agg) ----------------
// One half-wave per row, 8-deep independent loads. No LDS, tiny VGPR count
// -> max occupancy. Byte-identical to the round-0 232.6 us artifact.
__global__ __launch_bounds__(256) void gather_kernel(
    const unsigned short* __restrict__ xb,
    const int* __restrict__ order, const int* __restrict__ start,
    unsigned short* __restrict__ A1, int M) {
    int node = blockIdx.x * 8 + (threadIdx.x >> 5);
    if (node >= M) return;
    int lane32 = threadIdx.x & 31;
    const ushort4* xv = (const ushort4*)xb;
    float4 a0 = bf2f4(xv[(size_t)node * 32 + lane32]);  // self term
    float4 a1 = make_float4(0.f, 0.f, 0.f, 0.f);
    float4 a2 = a1, a3 = a1;
    int e0 = start[node], e1 = start[node + 1];
    int e = e0;
    for (; e + 8 <= e1; e += 8) {
        int s0 = order[e],     s1 = order[e + 1], s2 = order[e + 2], s3 = order[e + 3];
        int s4 = order[e + 4], s5 = order[e + 5], s6 = order[e + 6], s7 = order[e + 7];
        ushort4 u0 = xv[(size_t)s0 * 32 + lane32];
        ushort4 u1 = xv[(size_t)s1 * 32 + lane32];
        ushort4 u2 = xv[(size_t)s2 * 32 + lane32];
        ushort4 u3 = xv[(size_t)s3 * 32 + lane32];
        ushort4 u4 = xv[(size_t)s4 * 32 + lane32];
        ushort4 u5 = xv[(size_t)s5 * 32 + lane32];
        ushort4 u6 = xv[(size_t)s6 * 32 + lane32];
        ushort4 u7 = xv[(size_t)s7 * 32 + lane32];
        float4 v0 = bf2f4(u0), v1 = bf2f4(u1), v2 = bf2f4(u2), v3 = bf2f4(u3);
        float4 v4 = bf2f4(u4), v5 = bf2f4(u5), v6 = bf2f4(u6), v7 = bf2f4(u7);
        a0.x += v0.x; a0.y += v0.y; a0.z += v0.z; a0.w += v0.w;
        a1.x += v1.x; a1.y += v1.y; a1.z += v1.z; a1.w += v1.w;
        a2.x += v2.x; a2.y += v2.y; a2.z += v2.z; a2.w += v2.w;
        a3.x += v3.x; a3.y += v3.y; a3.z += v3.z; a3.w += v3.w;
        a0.x += v4.x; a0.y += v4.y; a0.z += v4.z; a0.w += v4.w;
        a1.x += v5.x; a1.y += v5.y; a1.z += v5.z; a1.w += v5.w;
        a2.x += v6.x; a2.y += v6.y; a2.z += v6.z; a2.w += v6.w;
        a3.x += v7.x; a3.y += v7.y; a3.z += v7.z; a3.w += v7.w;
    }
    for (; e + 4 <= e1; e += 4) {
        int s0 = order[e], s1 = order[e + 1], s2 = order[e + 2], s3 = order[e + 3];
        float4 v0 = bf2f4(xv[(size_t)s0 * 32 + lane32]);
        float4 v1 = bf2f4(xv[(size_t)s1 * 32 + lane32]);
        float4 v2 = bf2f4(xv[(size_t)s2 * 32 + lane32]);
        float4 v3 = bf2f4(xv[(size_t)s3 * 32 + lane32]);
        a0.x += v0.x; a0.y += v0.y; a0.z += v0.z; a0.w += v0.w;
        a1.x += v1.x; a1.y += v1.y; a1.z += v1.z; a1.w += v1.w;
        a2.x += v2.x; a2.y += v2.y; a2.z += v2.z; a2.w += v2.w;
        a3.x += v3.x; a3.y += v3.y; a3.z += v3.z; a3.w += v3.w;
    }
    for (; e < e1; ++e) {
        float4 v = bf2f4(xv[(size_t)order[e] * 32 + lane32]);
        a1.x += v.x; a1.y += v.y; a1.z += v.z; a1.w += v.w;
    }
    float4 t;
    t.x = (a0.x + a1.x) + (a2.x + a3.x);
    t.y = (a0.y + a1.y) + (a2.y + a3.y);
    t.z = (a0.z + a1.z) + (a2.z + a3.z);
    t.w = (a0.w + a1.w) + (a2.w + a3.w);
    ushort4 o;
    o.x = f2bf(t.x); o.y = f2bf(t.y); o.z = f2bf(t.z); o.w = f2bf(t.w);
    ((ushort4*)A1)[(size_t)node * 32 + lane32] = o;
}

// ---------------- GEMM1: h1 = bf16(A1 @ W1 + b1) + BN partials ----------------
// 128x256 tile, 512 threads (2x4 waves), K=128 (4 steps), double-buffered staging.
// Epilogue: BN partials (2 rows/block, plain stores) + h1 staged via LDS.
// Byte-identical to the round-0 artifact.
__global__ __launch_bounds__(512, 4) void gemm1_kernel(
    const unsigned short* __restrict__ A1, const unsigned short* __restrict__ W1t,
    const float* __restrict__ b1, unsigned short* __restrict__ h1,
    float* __restrict__ partials, int M) {
    constexpr int S = 4;
    constexpr int PA = 40, PB = 40, PH = 264;
    constexpr int STAGE = 128 * PA + 256 * PB;        // 15360 ushorts per buffer
    __shared__ __align__(16) unsigned short lds[128 * PH];  // 67.6 KB >= 2*STAGE
    unsigned short* h1t = lds;

    int tid = threadIdx.x;
    int wave = tid >> 6, lane = tid & 63;
    int wm = wave >> 2, wn = wave & 3;
    int l15 = lane & 15, q = lane >> 4;
    long row0 = (long)blockIdx.x * 128;

    int am = tid >> 2, ac = tid & 3;
    bf16x8 ar, br[2];
    auto loadAB = [&](int s) {
        ar = *(const bf16x8*)(A1 + (row0 + am) * F_IN + s * 32 + ac * 8);
#pragma unroll
        for (int i = 0; i < 2; ++i) {
            int ch = tid + i * 512;
            int m = ch >> 2, c = ch & 3;
            br[i] = *(const bf16x8*)(W1t + m * F_IN + s * 32 + c * 8);
        }
    };
    auto writeAB = [&](int buf) {
        unsigned short* As = lds + buf * STAGE;
        unsigned short* Bs = As + 128 * PA;
        *(bf16x8*)(&As[am * PA + ac * 8]) = ar;
#pragma unroll
        for (int i = 0; i < 2; ++i) {
            int ch = tid + i * 512;
            int m = ch >> 2, c = ch & 3;
            *(bf16x8*)(&Bs[m * PB + c * 8]) = br[i];
        }
    };

    f32x4 acc[4][4] = {};
    loadAB(0);
    writeAB(0);
#pragma unroll
    for (int s = 0; s < S; ++s) {
        if (s + 1 < S) loadAB(s + 1);
        __syncthreads();
        const unsigned short* As = lds + (s & 1) * STAGE;
        const unsigned short* Bs = As + 128 * PA;
        bf16x8 af[4], bfr[4];
#pragma unroll
        for (int mt = 0; mt < 4; ++mt)
            af[mt] = *(const bf16x8*)(&As[(wm * 64 + mt * 16 + l15) * PA + q * 8]);
#pragma unroll
        for (int nt = 0; nt < 4; ++nt)
            bfr[nt] = *(const bf16x8*)(&Bs[(wn * 64 + nt * 16 + l15) * PB + q * 8]);
#pragma unroll
        for (int mt = 0; mt < 4; ++mt)
#pragma unroll
            for (int nt = 0; nt < 4; ++nt)
                acc[mt][nt] = __builtin_amdgcn_mfma_f32_16x16x32_bf16(
                    af[mt], bfr[nt], acc[mt][nt], 0, 0, 0);
        if (s + 1 < S) writeAB((s + 1) & 1);
    }
    __syncthreads();  // staging reads done; alias h1t

    // ---- Epilogue: BN partials (2 rows/block) + staged h1 tile ----
#pragma unroll
    for (int nt = 0; nt < 4; ++nt) {
        int col = wn * 64 + nt * 16 + l15;
        float b = b1[col];
        float s = 0.f, ss = 0.f;
#pragma unroll
        for (int mt = 0; mt < 4; ++mt) {
#pragma unroll
            for (int r = 0; r < 4; ++r) {
                long row = row0 + wm * 64 + mt * 16 + q * 4 + r;
                float v = acc[mt][nt][r] + b;
                if (row < M) { s += v; ss += v * v; }
                h1t[(wm * 64 + mt * 16 + q * 4 + r) * PH + col] = f2bf(v);
            }
        }
        s += __shfl_xor(s, 16, 64);  s += __shfl_xor(s, 32, 64);
        ss += __shfl_xor(ss, 16, 64); ss += __shfl_xor(ss, 32, 64);
        if (lane < 16) {
            long pr = (long)blockIdx.x * 2 + wm;
            partials[pr * 512 + col] = s;
            partials[pr * 512 + 256 + col] = ss;
        }
    }
    __syncthreads();
    {   // contiguous stores: thread t -> row t>>2, 64-col segment (t&3)*64
        int srow = tid >> 2, scol = (tid & 3) * 64;
        unsigned short* dst = h1 + (row0 + srow) * DIM_H + scol;
        const unsigned short* srcp = &h1t[srow * PH + scol];
#pragma unroll
        for (int j = 0; j < 8; ++j)
            *(bf16x8*)(dst + j * 8) = *(const bf16x8*)(srcp + j * 8);
    }
}

// ---------------- fused GEMM2 + GEMM3, 128x256 tile, 512 threads ----------------
__global__ __launch_bounds__(512, 4) void gemm23_kernel(
    const unsigned short* __restrict__ h1, const unsigned short* __restrict__ W2t,
    const float* __restrict__ b2,
    const float* __restrict__ scale, const float* __restrict__ shift,
    const unsigned short* __restrict__ Wlt, const float* __restrict__ blin,
    float* __restrict__ out, int M) {
    constexpr int S = 8;
    constexpr int PA = 40, PB = 40, PH = 264;
    constexpr int STAGE = 128 * PA + 256 * PB;
    __shared__ __align__(16) unsigned short lds[128 * PH];
    unsigned short* h2t = lds;

    int tid = threadIdx.x;
    int wave = tid >> 6, lane = tid & 63;
    int wm = wave >> 2, wn = wave & 3;
    int l15 = lane & 15, q = lane >> 4;
    long row0 = (long)blockIdx.x * 128;

    int am = tid >> 2, ac = tid & 3;
    bf16x8 ar, br[2];
    auto loadAB = [&](int s) {
        ar = *(const bf16x8*)(h1 + (row0 + am) * DIM_H + s * 32 + ac * 8);
#pragma unroll
        for (int i = 0; i < 2; ++i) {
            int ch = tid + i * 512;
            int m = ch >> 2, c = ch & 3;
            br[i] = *(const bf16x8*)(W2t + m * DIM_H + s * 32 + c * 8);
        }
    };
    auto writeAB = [&](int s, int buf) {
        unsigned short* As = lds + buf * STAGE;
        unsigned short* Bs = As + 128 * PA;
        {
            int kb = s * 32 + ac * 8;
            float4 sc0 = *(const float4*)(scale + kb);
            float4 sc1 = *(const float4*)(scale + kb + 4);
            float4 sh0 = *(const float4*)(shift + kb);
            float4 sh1 = *(const float4*)(shift + kb + 4);
            float scv[8] = {sc0.x, sc0.y, sc0.z, sc0.w, sc1.x, sc1.y, sc1.z, sc1.w};
            float shv[8] = {sh0.x, sh0.y, sh0.z, sh0.w, sh1.x, sh1.y, sh1.z, sh1.w};
            bf16x8 v = ar;
#pragma unroll
            for (int j = 0; j < 8; ++j) {
                float f = bf2f((unsigned short)v[j]);
                f = fmaxf(f * scv[j] + shv[j], 0.f);
                v[j] = (short)f2bf(f);
            }
            *(bf16x8*)(&As[am * PA + ac * 8]) = v;
        }
#pragma unroll
        for (int i = 0; i < 2; ++i) {
            int ch = tid + i * 512;
            int m = ch >> 2, c = ch & 3;
            *(bf16x8*)(&Bs[m * PB + c * 8]) = br[i];
        }
    };

    f32x4 acc[4][4] = {};
    loadAB(0);
    writeAB(0, 0);
#pragma unroll
    for (int s = 0; s < S; ++s) {
        if (s + 1 < S) loadAB(s + 1);
        __syncthreads();
        const unsigned short* As = lds + (s & 1) * STAGE;
        const unsigned short* Bs = As + 128 * PA;
        bf16x8 af[4], bfr[4];
#pragma unroll
        for (int mt = 0; mt < 4; ++mt)
            af[mt] = *(const bf16x8*)(&As[(wm * 64 + mt * 16 + l15) * PA + q * 8]);
#pragma unroll
        for (int nt = 0; nt < 4; ++nt)
            bfr[nt] = *(const bf16x8*)(&Bs[(wn * 64 + nt * 16 + l15) * PB + q * 8]);
#pragma unroll
        for (int mt = 0; mt < 4; ++mt)
#pragma unroll
            for (int nt = 0; nt < 4; ++nt)
                acc[mt][nt] = __builtin_amdgcn_mfma_f32_16x16x32_bf16(
                    af[mt], bfr[nt], acc[mt][nt], 0, 0, 0);
        if (s + 1 < S) writeAB(s + 1, (s + 1) & 1);
    }
    __syncthreads();

#pragma unroll
    for (int nt = 0; nt < 4; ++nt) {
        int colL = wn * 64 + nt * 16 + l15;
        float b = b2[colL];
#pragma unroll
        for (int mt = 0; mt < 4; ++mt)
#pragma unroll
            for (int r = 0; r < 4; ++r) {
                int rowL = wm * 64 + mt * 16 + q * 4 + r;
                h2t[rowL * PH + colL] = f2bf(fmaxf(acc[mt][nt][r] + b, 0.f));
            }
    }
    __syncthreads();

    f32x4 acc3[3] = {};
#pragma unroll
    for (int s = 0; s < 8; ++s) {
        bf16x8 a3 = *(const bf16x8*)(&h2t[(wave * 16 + l15) * PH + s * 32 + q * 8]);
#pragma unroll
        for (int nt = 0; nt < 3; ++nt) {
            bf16x8 b3 = *(const bf16x8*)(Wlt + (nt * 16 + l15) * 256 + s * 32 + q * 8);
            acc3[nt] = __builtin_amdgcn_mfma_f32_16x16x32_bf16(a3, b3, acc3[nt], 0, 0, 0);
        }
    }
#pragma unroll
    for (int nt = 0; nt < 3; ++nt) {
        int col = nt * 16 + l15;
        if (col < N_CLASSES) {
            float b = blin[col];
#pragma unroll
            for (int r = 0; r < 4; ++r) {
                long row = row0 + wave * 16 + q * 4 + r;
                if (row < M) out[row * N_CLASSES + col] = acc3[nt][r] + b;
            }
        }
    }
}

extern "C" void kernel_launch(void* const* d_in, const int* in_sizes, int n_in,
                              void* d_out, int out_size, void* d_ws, size_t ws_size,
                              hipStream_t stream) {
    const float* x     = (const float*)d_in[0];
    const int*   ei    = (const int*)d_in[1];
    const float* W1    = (const float*)d_in[2];
    const float* b1    = (const float*)d_in[3];
    const float* gamma = (const float*)d_in[4];
    const float* beta  = (const float*)d_in[5];
    const float* W2    = (const float*)d_in[6];
    const float* b2    = (const float*)d_in[7];
    const float* Wlin  = (const float*)d_in[8];
    const float* blin  = (const float*)d_in[9];
    float* out = (float*)d_out;

    int M  = in_sizes[0] / F_IN;  // 50000
    int nE = in_sizes[1] / 2;     // 600000
    const int* srcIdx = ei;
    const int* dstIdx = ei + nE;
    int nB = (M + 255) / 256;     // 196 (scan blocks)
    int g128 = (M + 127) / 128;   // 391 (GEMM tiles)
    int XQ = M * 32;
    int ZQ = M / 4;               // hist only (cursor seeded by scan_kernel)

    unsigned short* h1bf  = (unsigned short*)d_ws;                     // M_PAD*256
    unsigned short* xb    = h1bf + (size_t)M_PAD * DIM_H;              // M_PAD*128
    unsigned short* A1bf  = xb + (size_t)M_PAD * F_IN;                 // M_PAD*128
    unsigned short* W1t   = A1bf + (size_t)M_PAD * F_IN;               // 256*128
    unsigned short* W2t   = W1t + DIM_H * F_IN;                        // 256*256
    unsigned short* Wlt   = W2t + DIM_H * DIM_H;                       // 64*256
    float*          partials = (float*)(Wlt + 64 * DIM_H);             // 2*g128*512
    float*          scale = partials + (size_t)800 * 512;              // 256
    float*          shift = scale + DIM_H;                             // 256
    int*            hist  = (int*)(shift + DIM_H);                     // M
    int*            cursor= hist + M;                                  // M (seeded by scan)
    int*            start = cursor + M;                                // M+1
    int*            order = start + (M + 1);                           // nE

    int tB = 256;
    prep_kernel<<<(XQ + 114688 + ZQ + 255) / 256, 256, 0, stream>>>(
        x, xb, W1, W2, Wlin, W1t, W2t, Wlt, hist, XQ, ZQ);
    hist_kernel<<<(nE + tB - 1) / tB, tB, 0, stream>>>(dstIdx, hist, nE);
    scan_kernel<<<nB, 256, 0, stream>>>(hist, start, cursor, M, nE);
    fill_kernel<<<(nE + tB - 1) / tB, tB, 0, stream>>>(srcIdx, dstIdx, cursor, order, nE);

    // standalone max-occupancy gather (round-0 proven form)
    gather_kernel<<<(M + 7) / 8, 256, 0, stream>>>(xb, order, start, A1bf, M);
    // GEMM1 + BN partials (plain stores)
    gemm1_kernel<<<g128, 512, 0, stream>>>(A1bf, W1t, b1, h1bf, partials, M);
    bn_reduce_kernel<<<DIM_H, 256, 0, stream>>>(partials, 2 * g128, gamma, beta, scale, shift, M);
    // fused GEMM2 + GEMM3
    gemm23_kernel<<<g128, 512, 0, stream>>>(h1bf, W2t, b2, scale, shift, Wlt, blin, out, M);
}

// Round 8
// 234.492 us; speedup vs baseline: 1.4998x; 1.0826x over previous
//
#include <hip/hip_runtime.h>

#define F_IN 128
#define DIM_H 256
#define N_CLASSES 40
#define BN_EPS 1e-5f
#define M_PAD 50176

typedef short bf16x8 __attribute__((ext_vector_type(8)));
typedef float f32x4 __attribute__((ext_vector_type(4)));

__device__ __forceinline__ unsigned short f2bf(float f) {
    union { float f; unsigned u; } v; v.f = f;
    unsigned r = v.u + 0x7fff + ((v.u >> 16) & 1);  // RNE
    return (unsigned short)(r >> 16);
}
__device__ __forceinline__ float bf2f(unsigned short u) {
    union { unsigned u; float f; } v; v.u = ((unsigned)u) << 16;
    return v.f;
}
__device__ __forceinline__ float4 bf2f4(ushort4 u) {
    return make_float4(bf2f(u.x), bf2f(u.y), bf2f(u.z), bf2f(u.w));
}

// ---------------- Phase A: histogram of dst ----------------
__global__ void hist_kernel(const int* __restrict__ dst, int* __restrict__ hist, int nE) {
    int e = blockIdx.x * blockDim.x + threadIdx.x;
    if (e >= nE) return;
    atomicAdd(&hist[dst[e]], 1);
}

// ---------------- Phase B: scan ----------------
__global__ void scan_blocks_kernel(const int* __restrict__ hist,
                                   int* __restrict__ blockSums, int M) {
    __shared__ int lds[256];
    int t = threadIdx.x;
    int i = blockIdx.x * 256 + t;
    lds[t] = (i < M) ? hist[i] : 0;
    __syncthreads();
    for (int off = 128; off > 0; off >>= 1) {
        if (t < off) lds[t] += lds[t + off];
        __syncthreads();
    }
    if (t == 0) blockSums[blockIdx.x] = lds[0];
}

__global__ void scan_final_kernel(const int* __restrict__ hist,
                                  const int* __restrict__ blockSums,
                                  int* __restrict__ start, int M, int nE) {
    __shared__ int lds[256];
    int t = threadIdx.x;
    lds[t] = (t < blockIdx.x) ? blockSums[t] : 0;
    __syncthreads();
    for (int o = 128; o > 0; o >>= 1) {
        if (t < o) lds[t] += lds[t + o];
        __syncthreads();
    }
    int off = lds[0];
    __syncthreads();
    int i = blockIdx.x * 256 + t;
    int orig = (i < M) ? hist[i] : 0;
    lds[t] = orig;
    __syncthreads();
    for (int o = 1; o < 256; o <<= 1) {
        int v = (t >= o) ? lds[t - o] : 0;
        __syncthreads();
        lds[t] += v;
        __syncthreads();
    }
    if (i < M) start[i] = off + lds[t] - orig;
    if (blockIdx.x == 0 && t == 0) start[M] = nE;
}

// ---------------- Phase C: bucket-fill src indices ----------------
__global__ void fill_kernel(const int* __restrict__ src, const int* __restrict__ dst,
                            const int* __restrict__ start, int* __restrict__ cursor,
                            int* __restrict__ order, int nE) {
    int e = blockIdx.x * blockDim.x + threadIdx.x;
    if (e >= nE) return;
    int d = dst[e];
    int pos = start[d] + atomicAdd(&cursor[d], 1);
    order[pos] = src[e];
}

// ---------------- prep: xb = bf16(x), weight transposes, hist+cursor zeroing ----------------
__global__ void prep_kernel(const float* __restrict__ x, unsigned short* __restrict__ xb,
                            const float* __restrict__ W1, const float* __restrict__ W2,
                            const float* __restrict__ Wl,
                            unsigned short* __restrict__ W1t,
                            unsigned short* __restrict__ W2t,
                            unsigned short* __restrict__ Wlt,
                            int* __restrict__ histz, int XQ, int ZQ) {
    int idx = blockIdx.x * 256 + threadIdx.x;
    if (idx < XQ) {
        float4 v = ((const float4*)x)[idx];
        ushort4 o;
        o.x = f2bf(v.x); o.y = f2bf(v.y); o.z = f2bf(v.z); o.w = f2bf(v.w);
        ((ushort4*)xb)[idx] = o;
        return;
    }
    int j = idx - XQ;
    if (j < 32768) {                    // W1t: [n=256][k=128]
        int n = j >> 7, k = j & 127;
        W1t[j] = f2bf(W1[k * DIM_H + n]);
    } else if (j < 32768 + 65536) {     // W2t: [n=256][k=256]
        int i = j - 32768;
        int n = i >> 8, k = i & 255;
        W2t[i] = f2bf(W2[k * DIM_H + n]);
    } else if (j < 32768 + 65536 + 16384) {  // Wlt: [n=64][k=256]
        int i = j - 98304;
        int n = i >> 8, k = i & 255;
        Wlt[i] = f2bf((n < N_CLASSES) ? Wl[k * N_CLASSES + n] : 0.f);
    } else {
        int z = j - 114688;
        if (z >= 0 && z < ZQ) ((int4*)histz)[z] = make_int4(0, 0, 0, 0);
    }
}

// ---------------- BN reduce ----------------
__global__ void bn_reduce_kernel(const float* __restrict__ partials, int R,
                                 const float* __restrict__ gamma,
                                 const float* __restrict__ beta,
                                 float* __restrict__ scale,
                                 float* __restrict__ shift, int M) {
    __shared__ float ls[256], lss[256];
    int c = blockIdx.x, t = threadIdx.x;
    float s = 0.f, ss = 0.f;
    for (int r = t; r < R; r += 256) {
        s += partials[(long)r * 512 + c];
        ss += partials[(long)r * 512 + 256 + c];
    }
    ls[t] = s; lss[t] = ss;
    __syncthreads();
    for (int o = 128; o > 0; o >>= 1) {
        if (t < o) { ls[t] += ls[t + o]; lss[t] += lss[t + o]; }
        __syncthreads();
    }
    if (t == 0) {
        float inv = 1.0f / (float)M;
        float mean = ls[0] * inv;
        float var = lss[0] * inv - mean * mean;
        float sc = gamma[c] * rsqrtf(var + BN_EPS);
        scale[c] = sc;
        shift[c] = beta[c] - mean * sc;
    }
}

// ---------------- standalone gather: A1 = bf16(x + agg) ----------------
// One half-wave per row, 8-deep independent loads. No LDS, tiny VGPR count
// -> 8 waves/SIMD (32 waves/CU): 2x the concurrent requests of the fused version.
__global__ __launch_bounds__(256) void gather_kernel(
    const unsigned short* __restrict__ xb,
    const int* __restrict__ order, const int* __restrict__ start,
    unsigned short* __restrict__ A1, int M) {
    int node = blockIdx.x * 8 + (threadIdx.x >> 5);
    if (node >= M) return;
    int lane32 = threadIdx.x & 31;
    const ushort4* xv = (const ushort4*)xb;
    float4 a0 = bf2f4(xv[(size_t)node * 32 + lane32]);  // self term
    float4 a1 = make_float4(0.f, 0.f, 0.f, 0.f);
    float4 a2 = a1, a3 = a1;
    int e0 = start[node], e1 = start[node + 1];
    int e = e0;
    for (; e + 8 <= e1; e += 8) {
        int s0 = order[e],     s1 = order[e + 1], s2 = order[e + 2], s3 = order[e + 3];
        int s4 = order[e + 4], s5 = order[e + 5], s6 = order[e + 6], s7 = order[e + 7];
        ushort4 u0 = xv[(size_t)s0 * 32 + lane32];
        ushort4 u1 = xv[(size_t)s1 * 32 + lane32];
        ushort4 u2 = xv[(size_t)s2 * 32 + lane32];
        ushort4 u3 = xv[(size_t)s3 * 32 + lane32];
        ushort4 u4 = xv[(size_t)s4 * 32 + lane32];
        ushort4 u5 = xv[(size_t)s5 * 32 + lane32];
        ushort4 u6 = xv[(size_t)s6 * 32 + lane32];
        ushort4 u7 = xv[(size_t)s7 * 32 + lane32];
        float4 v0 = bf2f4(u0), v1 = bf2f4(u1), v2 = bf2f4(u2), v3 = bf2f4(u3);
        float4 v4 = bf2f4(u4), v5 = bf2f4(u5), v6 = bf2f4(u6), v7 = bf2f4(u7);
        a0.x += v0.x; a0.y += v0.y; a0.z += v0.z; a0.w += v0.w;
        a1.x += v1.x; a1.y += v1.y; a1.z += v1.z; a1.w += v1.w;
        a2.x += v2.x; a2.y += v2.y; a2.z += v2.z; a2.w += v2.w;
        a3.x += v3.x; a3.y += v3.y; a3.z += v3.z; a3.w += v3.w;
        a0.x += v4.x; a0.y += v4.y; a0.z += v4.z; a0.w += v4.w;
        a1.x += v5.x; a1.y += v5.y; a1.z += v5.z; a1.w += v5.w;
        a2.x += v6.x; a2.y += v6.y; a2.z += v6.z; a2.w += v6.w;
        a3.x += v7.x; a3.y += v7.y; a3.z += v7.z; a3.w += v7.w;
    }
    for (; e + 4 <= e1; e += 4) {
        int s0 = order[e], s1 = order[e + 1], s2 = order[e + 2], s3 = order[e + 3];
        float4 v0 = bf2f4(xv[(size_t)s0 * 32 + lane32]);
        float4 v1 = bf2f4(xv[(size_t)s1 * 32 + lane32]);
        float4 v2 = bf2f4(xv[(size_t)s2 * 32 + lane32]);
        float4 v3 = bf2f4(xv[(size_t)s3 * 32 + lane32]);
        a0.x += v0.x; a0.y += v0.y; a0.z += v0.z; a0.w += v0.w;
        a1.x += v1.x; a1.y += v1.y; a1.z += v1.z; a1.w += v1.w;
        a2.x += v2.x; a2.y += v2.y; a2.z += v2.z; a2.w += v2.w;
        a3.x += v3.x; a3.y += v3.y; a3.z += v3.z; a3.w += v3.w;
    }
    for (; e < e1; ++e) {
        float4 v = bf2f4(xv[(size_t)order[e] * 32 + lane32]);
        a1.x += v.x; a1.y += v.y; a1.z += v.z; a1.w += v.w;
    }
    float4 t;
    t.x = (a0.x + a1.x) + (a2.x + a3.x);
    t.y = (a0.y + a1.y) + (a2.y + a3.y);
    t.z = (a0.z + a1.z) + (a2.z + a3.z);
    t.w = (a0.w + a1.w) + (a2.w + a3.w);
    ushort4 o;
    o.x = f2bf(t.x); o.y = f2bf(t.y); o.z = f2bf(t.z); o.w = f2bf(t.w);
    ((ushort4*)A1)[(size_t)node * 32 + lane32] = o;
}

// ---------------- GEMM1: h1 = bf16(A1 @ W1 + b1) + BN partials ----------------
// 128x256 tile, 512 threads (2x4 waves), K=128 (4 steps), double-buffered staging.
// Epilogue: BN partials (2 rows/block) + h1 staged via LDS for contiguous stores.
__global__ __launch_bounds__(512, 4) void gemm1_kernel(
    const unsigned short* __restrict__ A1, const unsigned short* __restrict__ W1t,
    const float* __restrict__ b1, unsigned short* __restrict__ h1,
    float* __restrict__ partials, int M) {
    constexpr int S = 4;
    constexpr int PA = 40, PB = 40, PH = 264;
    constexpr int STAGE = 128 * PA + 256 * PB;        // 15360 ushorts per buffer
    __shared__ __align__(16) unsigned short lds[128 * PH];  // 67.6 KB >= 2*STAGE
    unsigned short* h1t = lds;

    int tid = threadIdx.x;
    int wave = tid >> 6, lane = tid & 63;
    int wm = wave >> 2, wn = wave & 3;
    int l15 = lane & 15, q = lane >> 4;
    long row0 = (long)blockIdx.x * 128;

    int am = tid >> 2, ac = tid & 3;
    bf16x8 ar, br[2];
    auto loadAB = [&](int s) {
        ar = *(const bf16x8*)(A1 + (row0 + am) * F_IN + s * 32 + ac * 8);
#pragma unroll
        for (int i = 0; i < 2; ++i) {
            int ch = tid + i * 512;
            int m = ch >> 2, c = ch & 3;
            br[i] = *(const bf16x8*)(W1t + m * F_IN + s * 32 + c * 8);
        }
    };
    auto writeAB = [&](int buf) {
        unsigned short* As = lds + buf * STAGE;
        unsigned short* Bs = As + 128 * PA;
        *(bf16x8*)(&As[am * PA + ac * 8]) = ar;
#pragma unroll
        for (int i = 0; i < 2; ++i) {
            int ch = tid + i * 512;
            int m = ch >> 2, c = ch & 3;
            *(bf16x8*)(&Bs[m * PB + c * 8]) = br[i];
        }
    };

    f32x4 acc[4][4] = {};
    loadAB(0);
    writeAB(0);
#pragma unroll
    for (int s = 0; s < S; ++s) {
        if (s + 1 < S) loadAB(s + 1);
        __syncthreads();
        const unsigned short* As = lds + (s & 1) * STAGE;
        const unsigned short* Bs = As + 128 * PA;
        bf16x8 af[4], bfr[4];
#pragma unroll
        for (int mt = 0; mt < 4; ++mt)
            af[mt] = *(const bf16x8*)(&As[(wm * 64 + mt * 16 + l15) * PA + q * 8]);
#pragma unroll
        for (int nt = 0; nt < 4; ++nt)
            bfr[nt] = *(const bf16x8*)(&Bs[(wn * 64 + nt * 16 + l15) * PB + q * 8]);
#pragma unroll
        for (int mt = 0; mt < 4; ++mt)
#pragma unroll
            for (int nt = 0; nt < 4; ++nt)
                acc[mt][nt] = __builtin_amdgcn_mfma_f32_16x16x32_bf16(
                    af[mt], bfr[nt], acc[mt][nt], 0, 0, 0);
        if (s + 1 < S) writeAB((s + 1) & 1);
    }
    __syncthreads();  // staging reads done; alias h1t

    // ---- Epilogue: BN partials (2 rows/block) + staged h1 tile ----
#pragma unroll
    for (int nt = 0; nt < 4; ++nt) {
        int col = wn * 64 + nt * 16 + l15;
        float b = b1[col];
        float s = 0.f, ss = 0.f;
#pragma unroll
        for (int mt = 0; mt < 4; ++mt) {
#pragma unroll
            for (int r = 0; r < 4; ++r) {
                long row = row0 + wm * 64 + mt * 16 + q * 4 + r;
                float v = acc[mt][nt][r] + b;
                if (row < M) { s += v; ss += v * v; }
                h1t[(wm * 64 + mt * 16 + q * 4 + r) * PH + col] = f2bf(v);
            }
        }
        s += __shfl_xor(s, 16, 64);  s += __shfl_xor(s, 32, 64);
        ss += __shfl_xor(ss, 16, 64); ss += __shfl_xor(ss, 32, 64);
        if (lane < 16) {
            long pr = (long)blockIdx.x * 2 + wm;
            partials[pr * 512 + col] = s;
            partials[pr * 512 + 256 + col] = ss;
        }
    }
    __syncthreads();
    {   // contiguous stores: thread t -> row t>>2, 64-col segment (t&3)*64
        int srow = tid >> 2, scol = (tid & 3) * 64;
        unsigned short* dst = h1 + (row0 + srow) * DIM_H + scol;
        const unsigned short* srcp = &h1t[srow * PH + scol];
#pragma unroll
        for (int j = 0; j < 8; ++j)
            *(bf16x8*)(dst + j * 8) = *(const bf16x8*)(srcp + j * 8);
    }
}

// ---------------- fused GEMM2 + GEMM3, 128x256 tile, 512 threads (unchanged) ----------------
__global__ __launch_bounds__(512, 4) void gemm23_kernel(
    const unsigned short* __restrict__ h1, const unsigned short* __restrict__ W2t,
    const float* __restrict__ b2,
    const float* __restrict__ scale, const float* __restrict__ shift,
    const unsigned short* __restrict__ Wlt, const float* __restrict__ blin,
    float* __restrict__ out, int M) {
    constexpr int S = 8;
    constexpr int PA = 40, PB = 40, PH = 264;
    constexpr int STAGE = 128 * PA + 256 * PB;
    __shared__ __align__(16) unsigned short lds[128 * PH];
    unsigned short* h2t = lds;

    int tid = threadIdx.x;
    int wave = tid >> 6, lane = tid & 63;
    int wm = wave >> 2, wn = wave & 3;
    int l15 = lane & 15, q = lane >> 4;
    long row0 = (long)blockIdx.x * 128;

    int am = tid >> 2, ac = tid & 3;
    bf16x8 ar, br[2];
    auto loadAB = [&](int s) {
        ar = *(const bf16x8*)(h1 + (row0 + am) * DIM_H + s * 32 + ac * 8);
#pragma unroll
        for (int i = 0; i < 2; ++i) {
            int ch = tid + i * 512;
            int m = ch >> 2, c = ch & 3;
            br[i] = *(const bf16x8*)(W2t + m * DIM_H + s * 32 + c * 8);
        }
    };
    auto writeAB = [&](int s, int buf) {
        unsigned short* As = lds + buf * STAGE;
        unsigned short* Bs = As + 128 * PA;
        {
            int kb = s * 32 + ac * 8;
            float4 sc0 = *(const float4*)(scale + kb);
            float4 sc1 = *(const float4*)(scale + kb + 4);
            float4 sh0 = *(const float4*)(shift + kb);
            float4 sh1 = *(const float4*)(shift + kb + 4);
            float scv[8] = {sc0.x, sc0.y, sc0.z, sc0.w, sc1.x, sc1.y, sc1.z, sc1.w};
            float shv[8] = {sh0.x, sh0.y, sh0.z, sh0.w, sh1.x, sh1.y, sh1.z, sh1.w};
            bf16x8 v = ar;
#pragma unroll
            for (int j = 0; j < 8; ++j) {
                float f = bf2f((unsigned short)v[j]);
                f = fmaxf(f * scv[j] + shv[j], 0.f);
                v[j] = (short)f2bf(f);
            }
            *(bf16x8*)(&As[am * PA + ac * 8]) = v;
        }
#pragma unroll
        for (int i = 0; i < 2; ++i) {
            int ch = tid + i * 512;
            int m = ch >> 2, c = ch & 3;
            *(bf16x8*)(&Bs[m * PB + c * 8]) = br[i];
        }
    };

    f32x4 acc[4][4] = {};
    loadAB(0);
    writeAB(0, 0);
#pragma unroll
    for (int s = 0; s < S; ++s) {
        if (s + 1 < S) loadAB(s + 1);
        __syncthreads();
        const unsigned short* As = lds + (s & 1) * STAGE;
        const unsigned short* Bs = As + 128 * PA;
        bf16x8 af[4], bfr[4];
#pragma unroll
        for (int mt = 0; mt < 4; ++mt)
            af[mt] = *(const bf16x8*)(&As[(wm * 64 + mt * 16 + l15) * PA + q * 8]);
#pragma unroll
        for (int nt = 0; nt < 4; ++nt)
            bfr[nt] = *(const bf16x8*)(&Bs[(wn * 64 + nt * 16 + l15) * PB + q * 8]);
#pragma unroll
        for (int mt = 0; mt < 4; ++mt)
#pragma unroll
            for (int nt = 0; nt < 4; ++nt)
                acc[mt][nt] = __builtin_amdgcn_mfma_f32_16x16x32_bf16(
                    af[mt], bfr[nt], acc[mt][nt], 0, 0, 0);
        if (s + 1 < S) writeAB(s + 1, (s + 1) & 1);
    }
    __syncthreads();

#pragma unroll
    for (int nt = 0; nt < 4; ++nt) {
        int colL = wn * 64 + nt * 16 + l15;
        float b = b2[colL];
#pragma unroll
        for (int mt = 0; mt < 4; ++mt)
#pragma unroll
            for (int r = 0; r < 4; ++r) {
                int rowL = wm * 64 + mt * 16 + q * 4 + r;
                h2t[rowL * PH + colL] = f2bf(fmaxf(acc[mt][nt][r] + b, 0.f));
            }
    }
    __syncthreads();

    f32x4 acc3[3] = {};
#pragma unroll
    for (int s = 0; s < 8; ++s) {
        bf16x8 a3 = *(const bf16x8*)(&h2t[(wave * 16 + l15) * PH + s * 32 + q * 8]);
#pragma unroll
        for (int nt = 0; nt < 3; ++nt) {
            bf16x8 b3 = *(const bf16x8*)(Wlt + (nt * 16 + l15) * 256 + s * 32 + q * 8);
            acc3[nt] = __builtin_amdgcn_mfma_f32_16x16x32_bf16(a3, b3, acc3[nt], 0, 0, 0);
        }
    }
#pragma unroll
    for (int nt = 0; nt < 3; ++nt) {
        int col = nt * 16 + l15;
        if (col < N_CLASSES) {
            float b = blin[col];
#pragma unroll
            for (int r = 0; r < 4; ++r) {
                long row = row0 + wave * 16 + q * 4 + r;
                if (row < M) out[row * N_CLASSES + col] = acc3[nt][r] + b;
            }
        }
    }
}

extern "C" void kernel_launch(void* const* d_in, const int* in_sizes, int n_in,
                              void* d_out, int out_size, void* d_ws, size_t ws_size,
                              hipStream_t stream) {
    const float* x     = (const float*)d_in[0];
    const int*   ei    = (const int*)d_in[1];
    const float* W1    = (const float*)d_in[2];
    const float* b1    = (const float*)d_in[3];
    const float* gamma = (const float*)d_in[4];
    const float* beta  = (const float*)d_in[5];
    const float* W2    = (const float*)d_in[6];
    const float* b2    = (const float*)d_in[7];
    const float* Wlin  = (const float*)d_in[8];
    const float* blin  = (const float*)d_in[9];
    float* out = (float*)d_out;

    int M  = in_sizes[0] / F_IN;  // 50000
    int nE = in_sizes[1] / 2;     // 600000
    const int* srcIdx = ei;
    const int* dstIdx = ei + nE;
    int nB = (M + 255) / 256;     // 196
    int g128 = (M + 127) / 128;   // 391 (GEMM1 & GEMM23 tiles)
    int XQ = M * 32;
    int ZQ = 2 * M / 4;

    unsigned short* h1bf  = (unsigned short*)d_ws;                     // M_PAD*256
    unsigned short* xb    = h1bf + (size_t)M_PAD * DIM_H;              // M_PAD*128
    unsigned short* A1bf  = xb + (size_t)M_PAD * F_IN;                 // M_PAD*128
    unsigned short* W1t   = A1bf + (size_t)M_PAD * F_IN;               // 256*128
    unsigned short* W2t   = W1t + DIM_H * F_IN;                        // 256*256
    unsigned short* Wlt   = W2t + DIM_H * DIM_H;                       // 64*256
    float*          partials = (float*)(Wlt + 64 * DIM_H);             // 2*g128*512
    float*          scale = partials + (size_t)800 * 512;              // 256
    float*          shift = scale + DIM_H;                             // 256
    int*            hist  = (int*)(shift + DIM_H);                     // M
    int*            cursor= hist + M;                                  // M (adjacent)
    int*            start = cursor + M;                                // M+1
    int*            blockSums = start + (M + 1);                       // 256
    int*            order = blockSums + 256;                           // nE

    int tB = 256;
    prep_kernel<<<(XQ + 114688 + ZQ + 255) / 256, 256, 0, stream>>>(
        x, xb, W1, W2, Wlin, W1t, W2t, Wlt, hist, XQ, ZQ);
    hist_kernel<<<(nE + tB - 1) / tB, tB, 0, stream>>>(dstIdx, hist, nE);
    scan_blocks_kernel<<<nB, 256, 0, stream>>>(hist, blockSums, M);
    scan_final_kernel<<<nB, 256, 0, stream>>>(hist, blockSums, start, M, nE);
    fill_kernel<<<(nE + tB - 1) / tB, tB, 0, stream>>>(srcIdx, dstIdx, start, cursor, order, nE);

    // standalone max-occupancy gather
    gather_kernel<<<(M + 7) / 8, 256, 0, stream>>>(xb, order, start, A1bf, M);
    // GEMM1 + BN partials
    gemm1_kernel<<<g128, 512, 0, stream>>>(A1bf, W1t, b1, h1bf, partials, M);
    bn_reduce_kernel<<<DIM_H, 256, 0, stream>>>(partials, 2 * g128, gamma, beta, scale, shift, M);
    // fused GEMM2 + GEMM3
    gemm23_kernel<<<g128, 512, 0, stream>>>(h1bf, W2t, b2, scale, shift, Wlt, blin, out, M);
}